// Round 2
// baseline (601.724 us; speedup 1.0000x reference)
//
#include <hip/hip_runtime.h>
#include <cstdint>
#include <cstddef>

#define N_NODES 50000
#define N_EDGES 500000
#define N_GRAPHS 256
#define D_IN 768
#define D_H1 256
#define D_H2 128

typedef __attribute__((ext_vector_type(8))) __bf16 bf16x8;
typedef __attribute__((ext_vector_type(4))) float f32x4;

__device__ __forceinline__ float bf2f(uint32_t u) {
    union { uint32_t i; float f; } v; v.i = u << 16; return v.f;
}
__device__ __forceinline__ uint32_t f2bf(float f) {
    union { float f; uint32_t i; } v; v.f = f;
    uint32_t u = v.i;
    return (u + 0x7FFFu + ((u >> 16) & 1u)) >> 16;
}
// HW packed f32->bf16 (RNE), 2 elems/inst — keeps GEMM1's cvt cost off the
// critical path (16 inst per K-step/wave vs ~128 for manual bit-twiddling).
__device__ __forceinline__ uint32_t cvt_pk_bf16(float lo, float hi) {
    uint32_t r;
    asm("v_cvt_pk_bf16_f32 %0, %1, %2" : "=v"(r) : "v"(lo), "v"(hi));
    return r;
}

// pack one 64-lane chunk: chunk c holds A[mt*16+fr][kt*32+fq*8 .. +7] as 16B
__device__ __forceinline__ void pack_chunk(const float* __restrict__ p,
                                           uint16_t* __restrict__ out, int c) {
    float4 u = *(const float4*)p, v = *(const float4*)(p + 4);
    uint4 o;
    o.x = f2bf(u.x) | (f2bf(u.y) << 16);
    o.y = f2bf(u.z) | (f2bf(u.w) << 16);
    o.z = f2bf(v.x) | (f2bf(v.y) << 16);
    o.w = f2bf(v.z) | (f2bf(v.w) << 16);
    *(uint4*)(out + (size_t)c * 8) = o;
}

// ---------------- fused: packW1 + packW2 + degree-hist (x is NOT packed) -----
#define PACKW1_BLKS 192    // 32*24*64/256
#define PACKW2_BLKS 32     // 16*8*64/256
#define HIST256 1954
__global__ __launch_bounds__(256) void k_packw_hist(
    const float* __restrict__ W1l, const float* __restrict__ W1r, uint16_t* __restrict__ W1p,
    const float* __restrict__ W2l, const float* __restrict__ W2r, uint16_t* __restrict__ W2p,
    const int* __restrict__ e_dst, int* __restrict__ deg)
{
    int b = blockIdx.x;
    if (b < PACKW1_BLKS) {
        int c = b * 256 + threadIdx.x;
        int l = c & 63, t = c >> 6;
        int kt = t % 24, mt = t / 24;
        int fr = l & 15, fq = l >> 4;
        int row = mt * 16 + fr;
        const float* src = (row < 256) ? (W1l + (size_t)row * 768)
                                       : (W1r + (size_t)(row - 256) * 768);
        pack_chunk(src + kt * 32 + fq * 8, W1p, c);
    } else if (b < PACKW1_BLKS + PACKW2_BLKS) {
        int c = (b - PACKW1_BLKS) * 256 + threadIdx.x;
        int l = c & 63, t = c >> 6;
        int kt = t % 8, mt = t / 8;
        int fr = l & 15, fq = l >> 4;
        int row = mt * 16 + fr;
        const float* src = (row < 128) ? (W2l + (size_t)row * 256)
                                       : (W2r + (size_t)(row - 128) * 256);
        pack_chunk(src + kt * 32 + fq * 8, W2p, c);
    } else {
        int e = (b - PACKW1_BLKS - PACKW2_BLKS) * 256 + threadIdx.x;
        if (e < N_EDGES) atomicAdd(&deg[e_dst[e]], 1);
    }
}

// ---------------- single-kernel scan (196 co-resident blocks, spin on sums) --
// Publishes per-block total+1 into zeroed bsum, every block spins for all 196,
// scans them redundantly in LDS. Writes row_start AND cursor (=row_start copy)
// so k_fill needs no memset and no extra add.
__global__ __launch_bounds__(256) void k_scan(
    const int* __restrict__ deg, int* __restrict__ row_start, int* __restrict__ cursor,
    float* __restrict__ deg_inv, int* __restrict__ bsum, int n, int nb)
{
    __shared__ int buf[256];
    __shared__ int bbuf[256];
    int t = threadIdx.x, b = blockIdx.x, i = b * 256 + t;
    int v = (i < n) ? deg[i] : 0;
    buf[t] = v; __syncthreads();
    for (int off = 1; off < 256; off <<= 1) {
        int u = (t >= off) ? buf[t - off] : 0;
        __syncthreads(); buf[t] += u; __syncthreads();
    }
    if (t == 255) atomicExch(&bsum[b], buf[255] + 1);   // publish (device scope)
    int w = 0;
    if (t < nb) {
        do { w = atomicAdd(&bsum[t], 0); } while (w == 0);
        w -= 1;
    }
    bbuf[t] = w; __syncthreads();
    for (int off = 1; off < 256; off <<= 1) {
        int u = (t >= off) ? bbuf[t - off] : 0;
        __syncthreads(); bbuf[t] += u; __syncthreads();
    }
    int base = (b > 0) ? bbuf[b - 1] : 0;
    if (i < n) {
        int rs = base + buf[t] - v;      // global exclusive prefix
        row_start[i] = rs;
        cursor[i] = rs;
        deg_inv[i] = (v > 0) ? (1.0f / (float)v) : 0.0f;
    }
    if (b == 0 && t == 0) row_start[n] = N_EDGES;
}

// ---------------- GEMM1 (M=50000, N=512, K=768) + CSR-fill tail --------------
// A is read DIRECTLY from row-major f32 x (no packA pass): lane (fq,fr) loads
// 32B contiguous; fq-groups tile 128B per row -> coalesced. In-register
// v_cvt_pk_bf16_f32 feeds the MFMA. 8 waves (2m x 4n), wave tile 64x64 keeps
// acc at 64 VGPR so the f32 ping-pong staging (2x64 regs) fits under 256.
// XCD pair-swizzle: ids differing by 8 -> same XCD -> second N-half's A-read
// hits L2. CSR-fill blocks appended after the GEMM blocks.
#define G1_BLKS 784          // 49 groups of 16 ids -> 392 pairs, pair 391 idle
#define FILL_BLKS 977        // ceil(500000/512)
__global__ __launch_bounds__(512, 2) void k_gemm1_fill(
    const float* __restrict__ X, const uint16_t* __restrict__ Bp,
    uint16_t* __restrict__ Cl, uint16_t* __restrict__ Cr,
    const int* __restrict__ e_src, const int* __restrict__ e_dst,
    int* __restrict__ cursor, int* __restrict__ csr_src)
{
    if (blockIdx.x >= G1_BLKS) {                 // ---- CSR fill tail ----
        int e = (blockIdx.x - G1_BLKS) * 512 + threadIdx.x;
        if (e < N_EDGES) {
            int d = e_dst[e];
            int pos = atomicAdd(&cursor[d], 1);  // cursor pre-seeded = row_start
            csr_src[pos] = e_src[e];
        }
        return;
    }
    const int i = blockIdx.x;
    const int pr = (i >> 4) * 8 + (i & 7);       // M-slab index
    const int half = (i >> 3) & 1;               // N-half
    if (pr >= 391) return;
    const int KT = 24;
    const int tid = threadIdx.x;
    const int wave = tid >> 6, lane = tid & 63;
    const int fr = lane & 15, fq = lane >> 4;
    const int bm = pr * 128;
    const int wm = (wave >> 2) * 64, wn = (wave & 3) * 64;

    const float* aptr[4];
    #pragma unroll
    for (int mi = 0; mi < 4; ++mi) {
        int rb = bm + wm + mi * 16;
        if (rb > N_NODES - 16) rb = N_NODES - 16;    // M%16==0: clamp tile base
        aptr[mi] = X + (size_t)(rb + fr) * 768 + fq * 8;
    }
    const bf16x8* bp[4];
    #pragma unroll
    for (int ni = 0; ni < 4; ++ni) {
        int nt = ((half * 256 + wn) >> 4) + ni;
        bp[ni] = (const bf16x8*)Bp + (size_t)nt * KT * 64 + lane;
    }

    f32x4 acc[4][4] = {};
    float4 af0[8], af1[8];
    bf16x8 b0[4], b1[4];

    auto lA = [&](int kt, float4* d) {
        #pragma unroll
        for (int mi = 0; mi < 4; ++mi) {
            const float* p = aptr[mi] + kt * 32;
            d[mi * 2]     = *(const float4*)p;
            d[mi * 2 + 1] = *(const float4*)(p + 4);
        }
    };
    auto lB = [&](int kt, bf16x8* d) {
        #pragma unroll
        for (int ni = 0; ni < 4; ++ni) d[ni] = bp[ni][kt * 64];
    };
    auto step = [&](const float4* af, bf16x8* b) {
        bf16x8 a[4];
        #pragma unroll
        for (int mi = 0; mi < 4; ++mi) {
            union { bf16x8 v; uint32_t u[4]; } t;
            t.u[0] = cvt_pk_bf16(af[mi * 2].x,     af[mi * 2].y);
            t.u[1] = cvt_pk_bf16(af[mi * 2].z,     af[mi * 2].w);
            t.u[2] = cvt_pk_bf16(af[mi * 2 + 1].x, af[mi * 2 + 1].y);
            t.u[3] = cvt_pk_bf16(af[mi * 2 + 1].z, af[mi * 2 + 1].w);
            a[mi] = t.v;
        }
        #pragma unroll
        for (int mi = 0; mi < 4; ++mi)
            #pragma unroll
            for (int ni = 0; ni < 4; ++ni)
                acc[mi][ni] = __builtin_amdgcn_mfma_f32_16x16x32_bf16(
                    a[mi], b[ni], acc[mi][ni], 0, 0, 0);
    };

    lA(0, af0); lB(0, b0);
    for (int ks = 0; ks < KT; ks += 2) {
        lA(ks + 1, af1); lB(ks + 1, b1);
        step(af0, b0);
        if (ks + 2 < KT) { lA(ks + 2, af0); lB(ks + 2, b0); }
        step(af1, b1);
    }

    uint16_t* __restrict__ C = half ? Cr : Cl;   // split output [M][256] each
    #pragma unroll
    for (int mi = 0; mi < 4; ++mi) {
        #pragma unroll
        for (int r = 0; r < 4; ++r) {
            int row = bm + wm + mi * 16 + fq * 4 + r;
            if (row >= N_NODES) continue;
            #pragma unroll
            for (int ni = 0; ni < 4; ++ni) {
                int col = wn + ni * 16 + fr;     // 0..255 within half
                C[(size_t)row * 256 + col] = (uint16_t)f2bf(acc[mi][ni][r]);
            }
        }
    }
}

// ---------------- GEMM2: row-major bf16 A (h1), packed B ---------------------
__global__ __launch_bounds__(256, 2) void k_mgemm_rm(
    const uint16_t* __restrict__ A, const uint16_t* __restrict__ Bp,
    uint16_t* __restrict__ C, int M, int N, int KT)
{
    const int K = KT * 32;
    const int tid = threadIdx.x;
    const int wave = tid >> 6, lane = tid & 63;
    const int fr = lane & 15, fq = lane >> 4;
    const int bn = blockIdx.x * 256, bm = blockIdx.y * 128;
    const int wm = (wave >> 1) * 64, wn = (wave & 1) * 128;

    const uint16_t* ap[4];
    #pragma unroll
    for (int mi = 0; mi < 4; ++mi) {
        int rb = bm + wm + mi * 16;
        if (rb > M - 16) rb = M - 16;            // M%16==0
        ap[mi] = A + (size_t)(rb + fr) * K + fq * 8;
    }
    const bf16x8* bp[8];
    #pragma unroll
    for (int ni = 0; ni < 8; ++ni) {
        int nt = ((bn + wn) >> 4) + ni;
        bp[ni] = (const bf16x8*)Bp + (size_t)nt * KT * 64 + lane;
    }

    f32x4 acc[4][8] = {};
    bf16x8 a0[4], b0[8], a1[4], b1[8];

    auto lA = [&](int kt, bf16x8* d) {
        #pragma unroll
        for (int mi = 0; mi < 4; ++mi) d[mi] = *(const bf16x8*)(ap[mi] + kt * 32);
    };
    auto lB = [&](int kt, bf16x8* d) {
        #pragma unroll
        for (int ni = 0; ni < 8; ++ni) d[ni] = bp[ni][kt * 64];
    };
    auto step = [&](bf16x8* a, bf16x8* b) {
        #pragma unroll
        for (int mi = 0; mi < 4; ++mi)
            #pragma unroll
            for (int ni = 0; ni < 8; ++ni)
                acc[mi][ni] = __builtin_amdgcn_mfma_f32_16x16x32_bf16(
                    a[mi], b[ni], acc[mi][ni], 0, 0, 0);
    };

    lA(0, a0); lB(0, b0);
    for (int ks = 0; ks < KT; ks += 2) {
        lA(ks + 1, a1); lB(ks + 1, b1);
        step(a0, b0);
        if (ks + 2 < KT) { lA(ks + 2, a0); lB(ks + 2, b0); }
        step(a1, b1);
    }

    #pragma unroll
    for (int mi = 0; mi < 4; ++mi) {
        #pragma unroll
        for (int r = 0; r < 4; ++r) {
            int row = bm + wm + mi * 16 + fq * 4 + r;
            if (row >= M) continue;
            #pragma unroll
            for (int ni = 0; ni < 8; ++ni) {
                int col = bn + wn + ni * 16 + fr;
                C[(size_t)row * N + col] = (uint16_t)f2bf(acc[mi][ni][r]);
            }
        }
    }
}

// ---- fused aggregate layer1 -> ROW-MAJOR h1 (gather y1l, self y1r) ----------
__global__ __launch_bounds__(256) void k_agg1(
    const uint16_t* __restrict__ yl, const uint16_t* __restrict__ yr,
    const int* __restrict__ row_start, const int* __restrict__ csr,
    const float* __restrict__ deg_inv, const float* __restrict__ bias,
    uint16_t* __restrict__ h1)
{
    int node = blockIdx.x * 8 + (threadIdx.x >> 5);
    if (node >= N_NODES) return;
    int c = threadIdx.x & 31;                    // dim chunk: dims c*8 .. c*8+7
    int s = row_start[node], e = row_start[node + 1];
    float a[8] = {};
    int p = s;
    for (; p + 1 < e; p += 2) {
        uint4 t0 = *(const uint4*)(yl + (size_t)csr[p] * 256 + c * 8);
        uint4 t1 = *(const uint4*)(yl + (size_t)csr[p + 1] * 256 + c * 8);
        a[0] += bf2f(t0.x & 0xFFFF) + bf2f(t1.x & 0xFFFF);
        a[1] += bf2f(t0.x >> 16)    + bf2f(t1.x >> 16);
        a[2] += bf2f(t0.y & 0xFFFF) + bf2f(t1.y & 0xFFFF);
        a[3] += bf2f(t0.y >> 16)    + bf2f(t1.y >> 16);
        a[4] += bf2f(t0.z & 0xFFFF) + bf2f(t1.z & 0xFFFF);
        a[5] += bf2f(t0.z >> 16)    + bf2f(t1.z >> 16);
        a[6] += bf2f(t0.w & 0xFFFF) + bf2f(t1.w & 0xFFFF);
        a[7] += bf2f(t0.w >> 16)    + bf2f(t1.w >> 16);
    }
    if (p < e) {
        uint4 t0 = *(const uint4*)(yl + (size_t)csr[p] * 256 + c * 8);
        a[0] += bf2f(t0.x & 0xFFFF); a[1] += bf2f(t0.x >> 16);
        a[2] += bf2f(t0.y & 0xFFFF); a[3] += bf2f(t0.y >> 16);
        a[4] += bf2f(t0.z & 0xFFFF); a[5] += bf2f(t0.z >> 16);
        a[6] += bf2f(t0.w & 0xFFFF); a[7] += bf2f(t0.w >> 16);
    }
    float w = deg_inv[node];
    uint4 tx = *(const uint4*)(yr + (size_t)node * 256 + c * 8);
    float4 b0 = *(const float4*)(bias + c * 8);
    float4 b1 = *(const float4*)(bias + c * 8 + 4);
    float v0 = fmaxf(a[0] * w + bf2f(tx.x & 0xFFFF) + b0.x, 0.f);
    float v1 = fmaxf(a[1] * w + bf2f(tx.x >> 16)    + b0.y, 0.f);
    float v2 = fmaxf(a[2] * w + bf2f(tx.y & 0xFFFF) + b0.z, 0.f);
    float v3 = fmaxf(a[3] * w + bf2f(tx.y >> 16)    + b0.w, 0.f);
    float v4 = fmaxf(a[4] * w + bf2f(tx.z & 0xFFFF) + b1.x, 0.f);
    float v5 = fmaxf(a[5] * w + bf2f(tx.z >> 16)    + b1.y, 0.f);
    float v6 = fmaxf(a[6] * w + bf2f(tx.w & 0xFFFF) + b1.z, 0.f);
    float v7 = fmaxf(a[7] * w + bf2f(tx.w >> 16)    + b1.w, 0.f);
    uint4 o;
    o.x = f2bf(v0) | (f2bf(v1) << 16);
    o.y = f2bf(v2) | (f2bf(v3) << 16);
    o.z = f2bf(v4) | (f2bf(v5) << 16);
    o.w = f2bf(v6) | (f2bf(v7) << 16);
    *(uint4*)(h1 + (size_t)node * 256 + c * 8) = o;   // row-major, coalesced
}

// ---- fused aggregate layer2: h2 = relu(...), f32 out ----
__global__ __launch_bounds__(256) void k_agg2(
    const uint16_t* __restrict__ y, const int* __restrict__ row_start,
    const int* __restrict__ csr, const float* __restrict__ deg_inv,
    const float* __restrict__ bias, float* __restrict__ out)
{
    int node = blockIdx.x * 4 + (threadIdx.x >> 6);
    if (node >= N_NODES) return;
    int lane = threadIdx.x & 63;
    int s = row_start[node], e = row_start[node + 1];
    float a0 = 0.f, a1 = 0.f;
    int p = s;
    for (; p + 1 < e; p += 2) {
        uint32_t t0 = *(const uint32_t*)(y + (size_t)csr[p] * 256 + lane * 2);
        uint32_t t1 = *(const uint32_t*)(y + (size_t)csr[p + 1] * 256 + lane * 2);
        a0 += bf2f(t0 & 0xFFFF) + bf2f(t1 & 0xFFFF);
        a1 += bf2f(t0 >> 16)    + bf2f(t1 >> 16);
    }
    if (p < e) {
        uint32_t t0 = *(const uint32_t*)(y + (size_t)csr[p] * 256 + lane * 2);
        a0 += bf2f(t0 & 0xFFFF);
        a1 += bf2f(t0 >> 16);
    }
    float w = deg_inv[node];
    uint32_t tx = *(const uint32_t*)(y + (size_t)node * 256 + 128 + lane * 2);
    float2 b = *(const float2*)(bias + lane * 2);
    float2 o;
    o.x = fmaxf(a0 * w + bf2f(tx & 0xFFFF) + b.x, 0.f);
    o.y = fmaxf(a1 * w + bf2f(tx >> 16)    + b.y, 0.f);
    *(float2*)(out + (size_t)node * 128 + lane * 2) = o;
}

// ---------------- fused pool + head (one block per graph) --------------------
__global__ void k_poolhead(const float* __restrict__ h2, const int* __restrict__ batch,
                           const float* __restrict__ W3, const float* __restrict__ b3,
                           const float* __restrict__ W4, const float* __restrict__ b4,
                           float* __restrict__ out)
{
    int g = blockIdx.x;
    __shared__ int s_lo, s_hi;
    __shared__ float p[128];
    __shared__ float hid[64];
    __shared__ float logit[2];
    int t = threadIdx.x;  // 128
    if (t == 0) {
        int lo = 0, hi = N_NODES;
        while (lo < hi) { int m = (lo + hi) >> 1; if (batch[m] < g) lo = m + 1; else hi = m; }
        s_lo = lo;
        int lo2 = lo, hi2 = N_NODES;
        while (lo2 < hi2) { int m = (lo2 + hi2) >> 1; if (batch[m] < g + 1) lo2 = m + 1; else hi2 = m; }
        s_hi = lo2;
    }
    __syncthreads();
    float sum = 0.f;
    for (int i = s_lo; i < s_hi; ++i) sum += h2[(size_t)i * D_H2 + t];
    int cnt = s_hi - s_lo;
    p[t] = sum / (float)(cnt > 0 ? cnt : 1);
    __syncthreads();
    if (t < 64) {
        float s = b3[t];
        #pragma unroll 4
        for (int k = 0; k < 128; ++k) s = fmaf(p[k], W3[t * 128 + k], s);
        hid[t] = s;
    }
    __syncthreads();
    if (t < 2) {
        float l = b4[t];
        for (int k = 0; k < 64; ++k) l = fmaf(hid[k], W4[t * 64 + k], l);
        logit[t] = l;
    }
    __syncthreads();
    if (t == 0) {
        float m = fmaxf(logit[0], logit[1]);
        float e0 = expf(logit[0] - m), e1 = expf(logit[1] - m);
        float inv = 1.0f / (e0 + e1);
        out[g * 2 + 0] = e0 * inv;
        out[g * 2 + 1] = e1 * inv;
    }
}

extern "C" void kernel_launch(void* const* d_in, const int* in_sizes, int n_in,
                              void* d_out, int out_size, void* d_ws, size_t ws_size,
                              hipStream_t stream)
{
    const float* x     = (const float*)d_in[0];
    const int*   ei    = (const int*)d_in[1];
    const int*   batch = (const int*)d_in[2];
    const float* W1l   = (const float*)d_in[3];
    const float* b1l   = (const float*)d_in[4];
    const float* W1r   = (const float*)d_in[5];
    const float* W2l   = (const float*)d_in[6];
    const float* b2l   = (const float*)d_in[7];
    const float* W2r   = (const float*)d_in[8];
    const float* W3    = (const float*)d_in[9];
    const float* b3    = (const float*)d_in[10];
    const float* W4    = (const float*)d_in[11];
    const float* b4    = (const float*)d_in[12];
    float* out = (float*)d_out;

    const int* e_src = ei;
    const int* e_dst = ei + N_EDGES;

    char* ws = (char*)d_ws;
    size_t off = 0;
    auto alloc = [&](size_t bytes) -> void* {
        void* p = ws + off;
        off = (off + bytes + 255) & ~(size_t)255;
        return p;
    };
    int*      deg       = (int*)alloc((size_t)(N_NODES + 256) * 4);  // deg | bsum contiguous
    int*      bsum      = deg + N_NODES;
    int*      row_start = (int*)alloc((size_t)(N_NODES + 1) * 4);
    int*      cursor    = (int*)alloc((size_t)N_NODES * 4);
    int*      csr_src   = (int*)alloc((size_t)N_EDGES * 4);
    float*    deg_inv   = (float*)alloc((size_t)N_NODES * 4);
    uint16_t* W1p       = (uint16_t*)alloc((size_t)512 * 768 * 2);      // packed [W1l|W1r]
    uint16_t* W2p       = (uint16_t*)alloc((size_t)256 * 256 * 2);      // packed [W2l|W2r]
    uint16_t* y1        = (uint16_t*)alloc((size_t)N_NODES * 512 * 2);  // y1l | y1r
    uint16_t* h1        = (uint16_t*)alloc((size_t)N_NODES * 256 * 2);  // row-major h1
    uint16_t* y2        = (uint16_t*)alloc((size_t)N_NODES * 256 * 2);  // [h1l|h1r] row-major
    float*    h2        = (float*)alloc((size_t)N_NODES * 128 * 4);

    uint16_t* y1l = y1;
    uint16_t* y1r = y1 + (size_t)N_NODES * 256;

    hipMemsetAsync(deg, 0, (size_t)(N_NODES + 256) * 4, stream);  // deg + bsum

    // ---- pack W1/W2 + degree hist, one launch ----
    k_packw_hist<<<PACKW1_BLKS + PACKW2_BLKS + HIST256, 256, 0, stream>>>(
        W1l, W1r, W1p, W2l, W2r, W2p, e_dst, deg);

    // ---- single-kernel scan: row_start, cursor(=row_start), deg_inv ----
    int nscan = (N_NODES + 255) / 256;   // 196, always co-resident
    k_scan<<<nscan, 256, 0, stream>>>(deg, row_start, cursor, deg_inv, bsum, N_NODES, nscan);

    // ---- Layer 1 GEMM (direct f32 A + in-reg cvt) + CSR fill tail ----
    k_gemm1_fill<<<G1_BLKS + FILL_BLKS, 512, 0, stream>>>(
        x, W1p, y1l, y1r, e_src, e_dst, cursor, csr_src);
    k_agg1<<<(N_NODES + 7) / 8, 256, 0, stream>>>(y1l, y1r, row_start, csr_src, deg_inv, b1l, h1);

    // ---- Layer 2: y2 = h1 @ [W2l|W2r]^T  (M=50000, N=256, K=256) ----
    dim3 g2(1, (N_NODES + 127) / 128);
    k_mgemm_rm<<<g2, 256, 0, stream>>>(h1, W2p, y2, N_NODES, 256, 8);
    k_agg2<<<(N_NODES + 3) / 4, 256, 0, stream>>>(y2, row_start, csr_src, deg_inv, b2l, h2);

    // ---- Pool + head, one launch ----
    k_poolhead<<<N_GRAPHS, 128, 0, stream>>>(h2, batch, W3, b3, W4, b4, out);
}

// Round 3
// 481.865 us; speedup vs baseline: 1.2487x; 1.2487x over previous
//
#include <hip/hip_runtime.h>
#include <cstdint>
#include <cstddef>

#define N_NODES 50000
#define N_EDGES 500000
#define N_GRAPHS 256
#define D_IN 768
#define D_H1 256
#define D_H2 128

typedef __attribute__((ext_vector_type(8))) __bf16 bf16x8;
typedef __attribute__((ext_vector_type(4))) float f32x4;

__device__ __forceinline__ float bf2f(uint32_t u) {
    union { uint32_t i; float f; } v; v.i = u << 16; return v.f;
}
__device__ __forceinline__ uint32_t f2bf(float f) {
    union { float f; uint32_t i; } v; v.f = f;
    uint32_t u = v.i;
    return (u + 0x7FFFu + ((u >> 16) & 1u)) >> 16;
}

// pack one 64-lane chunk: chunk c holds A[mt*16+fr][kt*32+fq*8 .. +7] as 16B
__device__ __forceinline__ void pack_chunk(const float* __restrict__ p,
                                           uint16_t* __restrict__ out, int c) {
    float4 u = *(const float4*)p, v = *(const float4*)(p + 4);
    uint4 o;
    o.x = f2bf(u.x) | (f2bf(u.y) << 16);
    o.y = f2bf(u.z) | (f2bf(u.w) << 16);
    o.z = f2bf(v.x) | (f2bf(v.y) << 16);
    o.w = f2bf(v.z) | (f2bf(v.w) << 16);
    *(uint4*)(out + (size_t)c * 8) = o;
}

// ---------------- fused: packA(x) + packW1 + packW2 + degree-hist ------------
// Packed-fragment A is essential: GEMM fragment loads become contiguous 1KB
// bursts (R2's direct-f32-A read was 16 scattered lines/inst + VGPR spill ->
// 2.3x GEMM regression). The pack pass is memory-bound (~36us) and hides hist.
#define PACKA_BLKS 18750   // 3125 mtiles * 24 kt * 64 lanes / 256 (exact)
#define PACKW1_BLKS 192    // 32*24*64/256
#define PACKW2_BLKS 32     // 16*8*64/256
#define HIST256 1954
__global__ __launch_bounds__(256) void k_pack_hist(
    const float* __restrict__ x, uint16_t* __restrict__ xp,
    const float* __restrict__ W1l, const float* __restrict__ W1r, uint16_t* __restrict__ W1p,
    const float* __restrict__ W2l, const float* __restrict__ W2r, uint16_t* __restrict__ W2p,
    const int* __restrict__ e_dst, int* __restrict__ deg)
{
    int b = blockIdx.x;
    if (b < PACKA_BLKS) {
        int c = b * 256 + threadIdx.x;
        int l = c & 63, t = c >> 6;
        int kt = t % 24, mt = t / 24;
        int fr = l & 15, fq = l >> 4;
        pack_chunk(x + (size_t)(mt * 16 + fr) * 768 + kt * 32 + fq * 8, xp, c);
    } else if (b < PACKA_BLKS + PACKW1_BLKS) {
        int c = (b - PACKA_BLKS) * 256 + threadIdx.x;
        int l = c & 63, t = c >> 6;
        int kt = t % 24, mt = t / 24;
        int fr = l & 15, fq = l >> 4;
        int row = mt * 16 + fr;
        const float* src = (row < 256) ? (W1l + (size_t)row * 768)
                                       : (W1r + (size_t)(row - 256) * 768);
        pack_chunk(src + kt * 32 + fq * 8, W1p, c);
    } else if (b < PACKA_BLKS + PACKW1_BLKS + PACKW2_BLKS) {
        int c = (b - PACKA_BLKS - PACKW1_BLKS) * 256 + threadIdx.x;
        int l = c & 63, t = c >> 6;
        int kt = t % 8, mt = t / 8;
        int fr = l & 15, fq = l >> 4;
        int row = mt * 16 + fr;
        const float* src = (row < 128) ? (W2l + (size_t)row * 256)
                                       : (W2r + (size_t)(row - 128) * 256);
        pack_chunk(src + kt * 32 + fq * 8, W2p, c);
    } else {
        int e = (b - PACKA_BLKS - PACKW1_BLKS - PACKW2_BLKS) * 256 + threadIdx.x;
        if (e < N_EDGES) atomicAdd(&deg[e_dst[e]], 1);
    }
}

// ---------------- single-kernel scan (196 co-resident blocks, spin on sums) --
// Writes row_start AND cursor (=row_start) so fill needs no memset/add.
__global__ __launch_bounds__(256) void k_scan(
    const int* __restrict__ deg, int* __restrict__ row_start, int* __restrict__ cursor,
    float* __restrict__ deg_inv, int* __restrict__ bsum, int n, int nb)
{
    __shared__ int buf[256];
    __shared__ int bbuf[256];
    int t = threadIdx.x, b = blockIdx.x, i = b * 256 + t;
    int v = (i < n) ? deg[i] : 0;
    buf[t] = v; __syncthreads();
    for (int off = 1; off < 256; off <<= 1) {
        int u = (t >= off) ? buf[t - off] : 0;
        __syncthreads(); buf[t] += u; __syncthreads();
    }
    if (t == 255) atomicExch(&bsum[b], buf[255] + 1);   // publish (device scope)
    int w = 0;
    if (t < nb) {
        do { w = atomicAdd(&bsum[t], 0); } while (w == 0);
        w -= 1;
    }
    bbuf[t] = w; __syncthreads();
    for (int off = 1; off < 256; off <<= 1) {
        int u = (t >= off) ? bbuf[t - off] : 0;
        __syncthreads(); bbuf[t] += u; __syncthreads();
    }
    int base = (b > 0) ? bbuf[b - 1] : 0;
    if (i < n) {
        int rs = base + buf[t] - v;
        row_start[i] = rs;
        cursor[i] = rs;
        deg_inv[i] = (v > 0) ? (1.0f / (float)v) : 0.0f;
    }
    if (b == 0 && t == 0) row_start[n] = N_EDGES;
}

// ---------------- GEMM1 (M=50000, N=512, K=768) + CSR-fill tail --------------
// Barrier-free MFMA GEMM on packed operands, 128M x 256N per block, 4 waves
// (wave 64x128). Every fragment load is a coalesced 1KB burst; depth-2
// register ping-pong, no LDS. XCD pair-swizzle: two N-halves of one M-slab
// get ids differing by 8 -> same XCD -> A re-read is an L2 hit. Output split
// y1l/y1r so agg1 gathers a dense 25.6MB array.
#define G1_BLKS 784          // 49 groups of 16 ids -> 392 pairs, pair 391 idle
#define FILL_BLKS 1954       // ceil(500000/256)
__global__ __launch_bounds__(256, 2) void k_gemm1_fill(
    const uint16_t* __restrict__ Ap, const uint16_t* __restrict__ Bp,
    uint16_t* __restrict__ Cl, uint16_t* __restrict__ Cr,
    const int* __restrict__ e_src, const int* __restrict__ e_dst,
    int* __restrict__ cursor, int* __restrict__ csr_src)
{
    if (blockIdx.x >= G1_BLKS) {                 // ---- CSR fill tail ----
        int e = (blockIdx.x - G1_BLKS) * 256 + threadIdx.x;
        if (e < N_EDGES) {
            int d = e_dst[e];
            int pos = atomicAdd(&cursor[d], 1);  // cursor pre-seeded = row_start
            csr_src[pos] = e_src[e];
        }
        return;
    }
    const int i = blockIdx.x;
    const int pr = (i >> 4) * 8 + (i & 7);       // M-slab index
    const int half = (i >> 3) & 1;               // N-half
    if (pr >= 391) return;
    const int KT = 24;
    const int tid = threadIdx.x;
    const int wave = tid >> 6, lane = tid & 63;
    const int fr = lane & 15, fq = lane >> 4;
    const int bm = pr * 128;
    const int wm = (wave >> 1) * 64, wn = (wave & 1) * 128;
    const int mtiles = (N_NODES + 15) >> 4;

    const bf16x8* ap[4];
    const bf16x8* bp[8];
    #pragma unroll
    for (int mi = 0; mi < 4; ++mi) {
        int mt = ((bm + wm) >> 4) + mi;
        if (mt > mtiles - 1) mt = mtiles - 1;
        ap[mi] = (const bf16x8*)Ap + (size_t)mt * KT * 64 + lane;
    }
    #pragma unroll
    for (int ni = 0; ni < 8; ++ni) {
        int nt = ((half * 256 + wn) >> 4) + ni;
        bp[ni] = (const bf16x8*)Bp + (size_t)nt * KT * 64 + lane;
    }

    f32x4 acc[4][8] = {};
    bf16x8 a0[4], b0[8], a1[4], b1[8];

    auto lA = [&](int kt, bf16x8* d) {
        #pragma unroll
        for (int mi = 0; mi < 4; ++mi) d[mi] = ap[mi][kt * 64];
    };
    auto lB = [&](int kt, bf16x8* d) {
        #pragma unroll
        for (int ni = 0; ni < 8; ++ni) d[ni] = bp[ni][kt * 64];
    };
    auto step = [&](bf16x8* a, bf16x8* b) {
        #pragma unroll
        for (int mi = 0; mi < 4; ++mi)
            #pragma unroll
            for (int ni = 0; ni < 8; ++ni)
                acc[mi][ni] = __builtin_amdgcn_mfma_f32_16x16x32_bf16(
                    a[mi], b[ni], acc[mi][ni], 0, 0, 0);
    };

    lA(0, a0); lB(0, b0);
    for (int ks = 0; ks < KT; ks += 2) {
        lA(ks + 1, a1); lB(ks + 1, b1);
        step(a0, b0);
        if (ks + 2 < KT) { lA(ks + 2, a0); lB(ks + 2, b0); }
        step(a1, b1);
    }

    uint16_t* __restrict__ C = half ? Cr : Cl;   // split output [M][256] each
    #pragma unroll
    for (int mi = 0; mi < 4; ++mi) {
        #pragma unroll
        for (int r = 0; r < 4; ++r) {
            int row = bm + wm + mi * 16 + fq * 4 + r;
            if (row >= N_NODES) continue;
            #pragma unroll
            for (int ni = 0; ni < 8; ++ni) {
                int col = wn + ni * 16 + fr;     // 0..255 within half
                C[(size_t)row * 256 + col] = (uint16_t)f2bf(acc[mi][ni][r]);
            }
        }
    }
}

// ---------------- generic packed GEMM (layer 2) ------------------------------
__global__ __launch_bounds__(256, 2) void k_mgemm(
    const uint16_t* __restrict__ Ap, const uint16_t* __restrict__ Bp,
    uint16_t* __restrict__ C, int M, int N, int KT)
{
    const int tid = threadIdx.x;
    const int wave = tid >> 6, lane = tid & 63;
    const int fr = lane & 15, fq = lane >> 4;
    const int bn = blockIdx.x * 256, bm = blockIdx.y * 128;
    const int wm = (wave >> 1) * 64, wn = (wave & 1) * 128;
    const int mtiles = (M + 15) >> 4;

    const bf16x8* ap[4];
    const bf16x8* bp[8];
    #pragma unroll
    for (int mi = 0; mi < 4; ++mi) {
        int mt = ((bm + wm) >> 4) + mi;
        if (mt > mtiles - 1) mt = mtiles - 1;
        ap[mi] = (const bf16x8*)Ap + (size_t)mt * KT * 64 + lane;
    }
    #pragma unroll
    for (int ni = 0; ni < 8; ++ni) {
        int nt = ((bn + wn) >> 4) + ni;
        bp[ni] = (const bf16x8*)Bp + (size_t)nt * KT * 64 + lane;
    }

    f32x4 acc[4][8] = {};
    bf16x8 a0[4], b0[8], a1[4], b1[8];

    auto lA = [&](int kt, bf16x8* d) {
        #pragma unroll
        for (int mi = 0; mi < 4; ++mi) d[mi] = ap[mi][kt * 64];
    };
    auto lB = [&](int kt, bf16x8* d) {
        #pragma unroll
        for (int ni = 0; ni < 8; ++ni) d[ni] = bp[ni][kt * 64];
    };
    auto step = [&](bf16x8* a, bf16x8* b) {
        #pragma unroll
        for (int mi = 0; mi < 4; ++mi)
            #pragma unroll
            for (int ni = 0; ni < 8; ++ni)
                acc[mi][ni] = __builtin_amdgcn_mfma_f32_16x16x32_bf16(
                    a[mi], b[ni], acc[mi][ni], 0, 0, 0);
    };

    lA(0, a0); lB(0, b0);
    for (int ks = 0; ks < KT; ks += 2) {
        lA(ks + 1, a1); lB(ks + 1, b1);
        step(a0, b0);
        if (ks + 2 < KT) { lA(ks + 2, a0); lB(ks + 2, b0); }
        step(a1, b1);
    }

    #pragma unroll
    for (int mi = 0; mi < 4; ++mi) {
        #pragma unroll
        for (int r = 0; r < 4; ++r) {
            int row = bm + wm + mi * 16 + fq * 4 + r;
            if (row >= M) continue;
            #pragma unroll
            for (int ni = 0; ni < 8; ++ni) {
                int col = bn + wn + ni * 16 + fr;
                C[(size_t)row * N + col] = (uint16_t)f2bf(acc[mi][ni][r]);
            }
        }
    }
}

// ---- fused aggregate layer1 -> packed h1 (gather y1l, self y1r) -------------
// Half-wave per node, 8 dims/lane. 4-edge unroll: 4 independent 16B gathers in
// flight per iteration (avg deg ~10 -> latency-bound; MLP doubled vs 2-unroll).
__global__ __launch_bounds__(256) void k_agg1(
    const uint16_t* __restrict__ yl, const uint16_t* __restrict__ yr,
    const int* __restrict__ row_start, const int* __restrict__ csr,
    const float* __restrict__ deg_inv, const float* __restrict__ bias,
    uint16_t* __restrict__ h1p)
{
    int node = blockIdx.x * 8 + (threadIdx.x >> 5);
    if (node >= N_NODES) return;
    int c = threadIdx.x & 31;                    // dim chunk: dims c*8 .. c*8+7
    int s = row_start[node], e = row_start[node + 1];
    float a[8] = {};
    int p = s;
    auto accum = [&](uint4 t0) {
        a[0] += bf2f(t0.x & 0xFFFF); a[1] += bf2f(t0.x >> 16);
        a[2] += bf2f(t0.y & 0xFFFF); a[3] += bf2f(t0.y >> 16);
        a[4] += bf2f(t0.z & 0xFFFF); a[5] += bf2f(t0.z >> 16);
        a[6] += bf2f(t0.w & 0xFFFF); a[7] += bf2f(t0.w >> 16);
    };
    for (; p + 3 < e; p += 4) {
        uint4 t0 = *(const uint4*)(yl + (size_t)csr[p]     * 256 + c * 8);
        uint4 t1 = *(const uint4*)(yl + (size_t)csr[p + 1] * 256 + c * 8);
        uint4 t2 = *(const uint4*)(yl + (size_t)csr[p + 2] * 256 + c * 8);
        uint4 t3 = *(const uint4*)(yl + (size_t)csr[p + 3] * 256 + c * 8);
        accum(t0); accum(t1); accum(t2); accum(t3);
    }
    for (; p < e; ++p)
        accum(*(const uint4*)(yl + (size_t)csr[p] * 256 + c * 8));
    float w = deg_inv[node];
    uint4 tx = *(const uint4*)(yr + (size_t)node * 256 + c * 8);
    float4 b0 = *(const float4*)(bias + c * 8);
    float4 b1 = *(const float4*)(bias + c * 8 + 4);
    float v0 = fmaxf(a[0] * w + bf2f(tx.x & 0xFFFF) + b0.x, 0.f);
    float v1 = fmaxf(a[1] * w + bf2f(tx.x >> 16)    + b0.y, 0.f);
    float v2 = fmaxf(a[2] * w + bf2f(tx.y & 0xFFFF) + b0.z, 0.f);
    float v3 = fmaxf(a[3] * w + bf2f(tx.y >> 16)    + b0.w, 0.f);
    float v4 = fmaxf(a[4] * w + bf2f(tx.z & 0xFFFF) + b1.x, 0.f);
    float v5 = fmaxf(a[5] * w + bf2f(tx.z >> 16)    + b1.y, 0.f);
    float v6 = fmaxf(a[6] * w + bf2f(tx.w & 0xFFFF) + b1.z, 0.f);
    float v7 = fmaxf(a[7] * w + bf2f(tx.w >> 16)    + b1.w, 0.f);
    uint4 o;
    o.x = f2bf(v0) | (f2bf(v1) << 16);
    o.y = f2bf(v2) | (f2bf(v3) << 16);
    o.z = f2bf(v4) | (f2bf(v5) << 16);
    o.w = f2bf(v6) | (f2bf(v7) << 16);
    // packed chunk for GEMM2: mt=node/16, fr=node%16, kt=c/4, fq=c%4
    uint32_t addr = (((node >> 4) * 8 + (c >> 2)) * 64 + (c & 3) * 16 + (node & 15));
    *(uint4*)(h1p + (size_t)addr * 8) = o;
}

// ---- fused aggregate layer2: h2 = relu(...), f32 out, 4-edge unroll ---------
__global__ __launch_bounds__(256) void k_agg2(
    const uint16_t* __restrict__ y, const int* __restrict__ row_start,
    const int* __restrict__ csr, const float* __restrict__ deg_inv,
    const float* __restrict__ bias, float* __restrict__ out)
{
    int node = blockIdx.x * 4 + (threadIdx.x >> 6);
    if (node >= N_NODES) return;
    int lane = threadIdx.x & 63;
    int s = row_start[node], e = row_start[node + 1];
    float a0 = 0.f, a1 = 0.f;
    int p = s;
    for (; p + 3 < e; p += 4) {
        uint32_t t0 = *(const uint32_t*)(y + (size_t)csr[p]     * 256 + lane * 2);
        uint32_t t1 = *(const uint32_t*)(y + (size_t)csr[p + 1] * 256 + lane * 2);
        uint32_t t2 = *(const uint32_t*)(y + (size_t)csr[p + 2] * 256 + lane * 2);
        uint32_t t3 = *(const uint32_t*)(y + (size_t)csr[p + 3] * 256 + lane * 2);
        a0 += bf2f(t0 & 0xFFFF) + bf2f(t1 & 0xFFFF) + bf2f(t2 & 0xFFFF) + bf2f(t3 & 0xFFFF);
        a1 += bf2f(t0 >> 16)    + bf2f(t1 >> 16)    + bf2f(t2 >> 16)    + bf2f(t3 >> 16);
    }
    for (; p < e; ++p) {
        uint32_t t0 = *(const uint32_t*)(y + (size_t)csr[p] * 256 + lane * 2);
        a0 += bf2f(t0 & 0xFFFF);
        a1 += bf2f(t0 >> 16);
    }
    float w = deg_inv[node];
    uint32_t tx = *(const uint32_t*)(y + (size_t)node * 256 + 128 + lane * 2);
    float2 b = *(const float2*)(bias + lane * 2);
    float2 o;
    o.x = fmaxf(a0 * w + bf2f(tx & 0xFFFF) + b.x, 0.f);
    o.y = fmaxf(a1 * w + bf2f(tx >> 16)    + b.y, 0.f);
    *(float2*)(out + (size_t)node * 128 + lane * 2) = o;
}

// ---------------- fused pool + head (one block per graph) --------------------
__global__ void k_poolhead(const float* __restrict__ h2, const int* __restrict__ batch,
                           const float* __restrict__ W3, const float* __restrict__ b3,
                           const float* __restrict__ W4, const float* __restrict__ b4,
                           float* __restrict__ out)
{
    int g = blockIdx.x;
    __shared__ int s_lo, s_hi;
    __shared__ float p[128];
    __shared__ float hid[64];
    __shared__ float logit[2];
    int t = threadIdx.x;  // 128
    if (t == 0) {
        int lo = 0, hi = N_NODES;
        while (lo < hi) { int m = (lo + hi) >> 1; if (batch[m] < g) lo = m + 1; else hi = m; }
        s_lo = lo;
        int lo2 = lo, hi2 = N_NODES;
        while (lo2 < hi2) { int m = (lo2 + hi2) >> 1; if (batch[m] < g + 1) lo2 = m + 1; else hi2 = m; }
        s_hi = lo2;
    }
    __syncthreads();
    float sum = 0.f;
    for (int i = s_lo; i < s_hi; ++i) sum += h2[(size_t)i * D_H2 + t];
    int cnt = s_hi - s_lo;
    p[t] = sum / (float)(cnt > 0 ? cnt : 1);
    __syncthreads();
    if (t < 64) {
        float s = b3[t];
        #pragma unroll 4
        for (int k = 0; k < 128; ++k) s = fmaf(p[k], W3[t * 128 + k], s);
        hid[t] = s;
    }
    __syncthreads();
    if (t < 2) {
        float l = b4[t];
        for (int k = 0; k < 64; ++k) l = fmaf(hid[k], W4[t * 64 + k], l);
        logit[t] = l;
    }
    __syncthreads();
    if (t == 0) {
        float m = fmaxf(logit[0], logit[1]);
        float e0 = expf(logit[0] - m), e1 = expf(logit[1] - m);
        float inv = 1.0f / (e0 + e1);
        out[g * 2 + 0] = e0 * inv;
        out[g * 2 + 1] = e1 * inv;
    }
}

extern "C" void kernel_launch(void* const* d_in, const int* in_sizes, int n_in,
                              void* d_out, int out_size, void* d_ws, size_t ws_size,
                              hipStream_t stream)
{
    const float* x     = (const float*)d_in[0];
    const int*   ei    = (const int*)d_in[1];
    const int*   batch = (const int*)d_in[2];
    const float* W1l   = (const float*)d_in[3];
    const float* b1l   = (const float*)d_in[4];
    const float* W1r   = (const float*)d_in[5];
    const float* W2l   = (const float*)d_in[6];
    const float* b2l   = (const float*)d_in[7];
    const float* W2r   = (const float*)d_in[8];
    const float* W3    = (const float*)d_in[9];
    const float* b3    = (const float*)d_in[10];
    const float* W4    = (const float*)d_in[11];
    const float* b4    = (const float*)d_in[12];
    float* out = (float*)d_out;

    const int* e_src = ei;
    const int* e_dst = ei + N_EDGES;

    char* ws = (char*)d_ws;
    size_t off = 0;
    auto alloc = [&](size_t bytes) -> void* {
        void* p = ws + off;
        off = (off + bytes + 255) & ~(size_t)255;
        return p;
    };
    int*      deg       = (int*)alloc((size_t)(N_NODES + 256) * 4);  // deg | bsum
    int*      bsum      = deg + N_NODES;
    int*      row_start = (int*)alloc((size_t)(N_NODES + 1) * 4);
    int*      cursor    = (int*)alloc((size_t)N_NODES * 4);
    int*      csr_src   = (int*)alloc((size_t)N_EDGES * 4);
    float*    deg_inv   = (float*)alloc((size_t)N_NODES * 4);
    uint16_t* W1p       = (uint16_t*)alloc((size_t)512 * 768 * 2);      // packed [W1l|W1r]
    uint16_t* W2p       = (uint16_t*)alloc((size_t)256 * 256 * 2);      // packed [W2l|W2r]
    uint16_t* xp        = (uint16_t*)alloc((size_t)N_NODES * D_IN * 2); // packed x; reused later
    uint16_t* y1        = (uint16_t*)alloc((size_t)N_NODES * 512 * 2);  // y1l | y1r
    uint16_t* h1p       = (uint16_t*)alloc((size_t)N_NODES * 256 * 2);  // packed h1

    uint16_t* y1l = y1;
    uint16_t* y1r = y1 + (size_t)N_NODES * 256;
    uint16_t* y2 = xp;                                       // [h1l|h1r] row-major, 25.6MB
    float*    h2 = (float*)(xp + (size_t)N_NODES * 256);     // f32, 25.6MB (fits in xp region)

    hipMemsetAsync(deg, 0, (size_t)(N_NODES + 256) * 4, stream);  // deg + bsum

    // ---- pack (x, W1, W2) + degree hist, one launch ----
    k_pack_hist<<<PACKA_BLKS + PACKW1_BLKS + PACKW2_BLKS + HIST256, 256, 0, stream>>>(
        x, xp, W1l, W1r, W1p, W2l, W2r, W2p, e_dst, deg);

    // ---- single-kernel scan: row_start, cursor(=row_start), deg_inv ----
    int nscan = (N_NODES + 255) / 256;   // 196, always co-resident
    k_scan<<<nscan, 256, 0, stream>>>(deg, row_start, cursor, deg_inv, bsum, N_NODES, nscan);

    // ---- Layer 1 GEMM (packed A, XCD pair-swizzle) + CSR fill tail ----
    k_gemm1_fill<<<G1_BLKS + FILL_BLKS, 256, 0, stream>>>(
        xp, W1p, y1l, y1r, e_src, e_dst, cursor, csr_src);
    k_agg1<<<(N_NODES + 7) / 8, 256, 0, stream>>>(y1l, y1r, row_start, csr_src, deg_inv, b1l, h1p);

    // ---- Layer 2: y2 = h1 @ [W2l|W2r]^T  (M=50000, N=256, K=256) ----
    dim3 g2(1, (N_NODES + 127) / 128);
    k_mgemm<<<g2, 256, 0, stream>>>(h1p, W2p, y2, N_NODES, 256, 8);
    k_agg2<<<(N_NODES + 3) / 4, 256, 0, stream>>>(y2, row_start, csr_src, deg_inv, b2l, h2);

    // ---- Pool + head, one launch ----
    k_poolhead<<<N_GRAPHS, 128, 0, stream>>>(h2, batch, W3, b3, W4, b4, out);
}